// Round 2
// baseline (110.606 us; speedup 1.0000x reference)
//
#include <hip/hip_runtime.h>
#include <hip/hip_bf16.h>
#include <cmath>

#define Tt 2048
#define Hh 8

using u16x8 = __attribute__((ext_vector_type(8))) unsigned short;
using s16x8 = __attribute__((ext_vector_type(8))) short;
using f32x4 = __attribute__((ext_vector_type(4))) float;

__device__ __forceinline__ unsigned short f2bf(float f) {
  __hip_bfloat16 b = __float2bfloat16(f);
  return *reinterpret_cast<unsigned short*>(&b);
}

// async global->LDS, 16B/lane; dest = uniform base + lane*16 (m97/m104)
#define GLD16(gp, lp)                                                        \
  __builtin_amdgcn_global_load_lds(                                          \
      (const __attribute__((address_space(1))) unsigned int*)(gp),           \
      (__attribute__((address_space(3))) unsigned int*)(lp), 16, 0, 0)

// ---- prep: z<4 -> transpose+cvt weight z into WTall; z==4 -> cvt h ---------
__global__ __launch_bounds__(256) void prep_all(
    const float* __restrict__ s0, const float* __restrict__ s1,
    const float* __restrict__ s2, const float* __restrict__ s3,
    unsigned short* __restrict__ d,
    const float* __restrict__ hsrc, unsigned short* __restrict__ hdst) {
  int tid = threadIdx.x;
  if (blockIdx.z == 4) {
    int gid = ((int)blockIdx.y * 8 + blockIdx.x) * 256 + tid;  // 0..16383
    #pragma unroll
    for (int s = 0; s < 16; ++s) {
      size_t i = ((size_t)s * 16384 + gid) * 8;
      const float4* g = (const float4*)&hsrc[i];
      float4 f0 = g[0], f1 = g[1];
      u16x8 o = {f2bf(f0.x), f2bf(f0.y), f2bf(f0.z), f2bf(f0.w),
                 f2bf(f1.x), f2bf(f1.y), f2bf(f1.z), f2bf(f1.w)};
      *(u16x8*)&hdst[i] = o;
    }
    return;
  }
  __shared__ unsigned short tile[64 * 65];
  const float* srcs[4] = {s0, s1, s2, s3};
  const float* src = srcs[blockIdx.z];
  unsigned short* dst = d + (size_t)blockIdx.z * 512 * 512;
  int n0 = blockIdx.x * 64, k0 = blockIdx.y * 64;
  int tx = tid & 63, ty = tid >> 6;
  #pragma unroll
  for (int i = 0; i < 16; ++i) {
    int k = ty * 16 + i;
    tile[k * 65 + tx] = f2bf(src[(k0 + k) * 512 + n0 + tx]);
  }
  __syncthreads();
  #pragma unroll
  for (int i = 0; i < 16; ++i) {
    int n = ty * 16 + i;
    dst[(n0 + n) * 512 + k0 + tx] = tile[tx * 65 + n];
  }
}

// -------- fused QKV GEMM v2: 128x128 tile (m93/m97 shape), dbuf LDS ---------
// grid (32, 12) = 384 blocks; 4 waves in 2x2, each wave owns 64x64 out.
// XCD swizzle: 48 blocks/XCD (1.5 n-columns). Q,K out: (B,H,T,C). V: (B,H,C,T).
__global__ __launch_bounds__(256) void qkv_fused(
    const unsigned short* __restrict__ Hb,     // (4096,512) bf16
    const unsigned short* __restrict__ WTall,  // (1536,512) bf16 [n][k]
    const float* __restrict__ qnw, const float* __restrict__ knw,
    const float* __restrict__ rcos, const float* __restrict__ rsin,
    unsigned short* __restrict__ Qw, unsigned short* __restrict__ Kw,
    unsigned short* __restrict__ Vw) {
  // 64 KB: buffer b at S + b*16384 (A 128x64 = 8192 shorts, B 128x64 = 8192)
  __shared__ alignas(16) unsigned short S[32768];
  int tid = threadIdx.x;
  int wave = tid >> 6, lane = tid & 63;
  int ln = lane & 15, qd = lane >> 4;
  int wm = wave >> 1, wn = wave & 1;
  int id = (int)blockIdx.x + 32 * (int)blockIdx.y;   // 0..383
  int sw = (id & 7) * 48 + (id >> 3);                // bijective XCD chunks
  int m0 = (sw & 31) * 128;
  int n0 = (sw >> 5) * 128;

  f32x4 acc[4][4];
  #pragma unroll
  for (int mi = 0; mi < 4; ++mi)
    #pragma unroll
    for (int ni = 0; ni < 4; ++ni) acc[mi][ni] = f32x4{0.f, 0.f, 0.f, 0.f};

  auto stage = [&](int k0, int buf) {
    char* Apt = (char*)(S + buf * 16384);
    char* Bpt = (char*)(S + buf * 16384 + 8192);
    #pragma unroll
    for (int s = 0; s < 4; ++s) {    // A: 16 chunks of 1 KB
      int q = s * 4 + wave;
      int L = q * 64 + lane;
      int row = L >> 3;
      int cb = (L & 7) ^ (row & 7);
      GLD16(&Hb[(size_t)(m0 + row) * 512 + k0 + cb * 8], Apt + q * 1024);
    }
    #pragma unroll
    for (int s = 0; s < 4; ++s) {    // B: 16 chunks
      int q = s * 4 + wave;
      int L = q * 64 + lane;
      int row = L >> 3;
      int cb = (L & 7) ^ (row & 7);
      GLD16(&WTall[(size_t)(n0 + row) * 512 + k0 + cb * 8], Bpt + q * 1024);
    }
  };

  stage(0, 0);
  __syncthreads();
  for (int it = 0; it < 8; ++it) {
    int cur = it & 1;
    if (it < 7) stage((it + 1) * 64, cur ^ 1);
    const char* Al = (const char*)(S + cur * 16384);
    const char* Bl = (const char*)(S + cur * 16384 + 8192);
    #pragma unroll
    for (int half = 0; half < 2; ++half) {
      s16x8 af[4], bfr[4];
      #pragma unroll
      for (int mi = 0; mi < 4; ++mi) {
        int ar = wm * 64 + mi * 16 + ln;
        int cbp = (qd + half * 4) ^ (ar & 7);
        af[mi] = *(const s16x8*)(Al + ar * 128 + cbp * 16);
      }
      #pragma unroll
      for (int ni = 0; ni < 4; ++ni) {
        int br = wn * 64 + ni * 16 + ln;
        int cbp = (qd + half * 4) ^ (br & 7);
        bfr[ni] = *(const s16x8*)(Bl + br * 128 + cbp * 16);
      }
      #pragma unroll
      for (int mi = 0; mi < 4; ++mi)
        #pragma unroll
        for (int ni = 0; ni < 4; ++ni)
          acc[mi][ni] = __builtin_amdgcn_mfma_f32_16x16x32_bf16(
              af[mi], bfr[ni], acc[mi][ni], 0, 0, 0);
    }
    __syncthreads();   // single drain: loads for it+1 had full MFMA phase
  }

  int ng = n0 + wn * 64;             // this wave's global n start (one head)
  int mat = ng >> 9;                 // 0=Q 1=K 2=V
  int head = (ng >> 6) & 7;
  const float* nw = (mat == 0) ? qnw : knw;
  bool do_rope = (mat < 2);
  int mrow0 = m0 + wm * 64;          // 64 rows per wave, never crosses batch
  int b = mrow0 >> 11, tb = mrow0 & (Tt - 1);

  unsigned short* Wl = S + wave * 4608;   // wave-private [64][72]
  #pragma unroll
  for (int mi = 0; mi < 4; ++mi) {
    float vals[4][4];
    #pragma unroll
    for (int ni = 0; ni < 4; ++ni)
      #pragma unroll
      for (int r = 0; r < 4; ++r) vals[ni][r] = acc[mi][ni][r];

    if (do_rope) {
      #pragma unroll
      for (int r = 0; r < 4; ++r) {
        float ss = 0.f;
        #pragma unroll
        for (int ni = 0; ni < 4; ++ni) ss += vals[ni][r] * vals[ni][r];
        ss += __shfl_xor(ss, 1, 64);
        ss += __shfl_xor(ss, 2, 64);
        ss += __shfl_xor(ss, 4, 64);
        ss += __shfl_xor(ss, 8, 64);
        float nrm = rsqrtf(ss * (1.0f / 64.0f) + 1e-6f);
        #pragma unroll
        for (int ni = 0; ni < 4; ++ni) vals[ni][r] *= nrm;
      }
      #pragma unroll
      for (int ni = 0; ni < 4; ++ni) {
        float w = nw[ni * 16 + ln];
        #pragma unroll
        for (int r = 0; r < 4; ++r) vals[ni][r] *= w;
      }
      float res[4][4];
      #pragma unroll
      for (int r = 0; r < 4; ++r) {
        int t = tb + mi * 16 + qd * 4 + r;
        #pragma unroll
        for (int ni = 0; ni < 4; ++ni) {
          int c = ni * 16 + ln;
          float cs = rcos[t * 64 + c];
          float sn = rsin[t * 64 + c];
          float part = vals[ni ^ 2][r];
          float rot = (ni < 2) ? -part : part;
          res[ni][r] = vals[ni][r] * cs + rot * sn;
        }
      }
      #pragma unroll
      for (int ni = 0; ni < 4; ++ni)
        #pragma unroll
        for (int r = 0; r < 4; ++r) vals[ni][r] = res[ni][r];
    }

    if (mat < 2) {   // [t_local 64][c 64] pad 72, wave-private
      #pragma unroll
      for (int ni = 0; ni < 4; ++ni)
        #pragma unroll
        for (int r = 0; r < 4; ++r)
          Wl[(mi * 16 + qd * 4 + r) * 72 + ni * 16 + ln] = f2bf(vals[ni][r]);
    } else {         // V: [c 64][t_local 64] pad 72
      #pragma unroll
      for (int ni = 0; ni < 4; ++ni)
        #pragma unroll
        for (int r = 0; r < 4; ++r)
          Wl[(ni * 16 + ln) * 72 + mi * 16 + qd * 4 + r] = f2bf(vals[ni][r]);
    }
  }

  if (mat < 2) {
    unsigned short* Og =
        ((mat == 0) ? Qw : Kw) + (((size_t)b * Hh + head) * Tt + tb) * 64;
    #pragma unroll
    for (int i = 0; i < 8; ++i) {    // 64 rows x 64 = 512 chunks
      int idx = i * 64 + lane;
      int rr = idx >> 3, cc = (idx & 7) * 8;
      *(u16x8*)&Og[rr * 64 + cc] = *(const u16x8*)&Wl[rr * 72 + cc];
    }
  } else {
    unsigned short* Og = Vw + ((size_t)b * Hh + head) * 64 * 2048 + tb;
    #pragma unroll
    for (int i = 0; i < 8; ++i) {    // 64 c-rows x 64 t = 512 chunks
      int idx = i * 64 + lane;
      int rr = idx >> 3, cc = (idx & 7) * 8;
      *(u16x8*)&Og[(size_t)rr * 2048 + cc] = *(const u16x8*)&Wl[rr * 72 + cc];
    }
  }
}

// ---------- MFMA sliding-window attention: 64 queries / block ---------------
// Q,K: (B,H,T,C); V: (B,H,C,T). AO: (B,T,H,C). 48 KB LDS.
// K and V staged via async global_load_lds into LINEAR rows with XOR
// chunk-swizzle applied on the per-lane GLOBAL source address (rule-21).
__global__ __launch_bounds__(256) void attn_mfma(
    const unsigned short* __restrict__ Q,
    const unsigned short* __restrict__ K,
    const unsigned short* __restrict__ Vg,
    unsigned short* __restrict__ AO) {
  __shared__ alignas(16) unsigned short KP[192 * 64];  // K tile; then P[64][192]
  __shared__ alignas(16) unsigned short Vt[64 * 192];  // [c][kk] swizzled
  int tid = threadIdx.x;
  int wave = tid >> 6, lane = tid & 63;
  int ln = lane & 15, qd = lane >> 4;
  int id = (int)blockIdx.x + 32 * (int)blockIdx.y;
  int swb = (id & 7) * 64 + (id >> 3);
  int t0 = (swb & 31) * 64, bh = swb >> 5;
  int kb = t0 - 128;
  int q0 = wave * 16;

  const unsigned short* Kg = K + (size_t)bh * Tt * 64;
  const unsigned short* Vb = Vg + (size_t)bh * 64 * 2048;

  // --- async stage K: 192 rows x 64 shorts = 24 chunks of 1 KB ---
  #pragma unroll
  for (int s = 0; s < 6; ++s) {
    int q = s * 4 + wave;
    int L = q * 64 + lane;
    int row = L >> 3;
    int kg = kb + row; if (kg < 0) kg = 0;   // garbage row, masked by P=0
    int cb = (L & 7) ^ (row & 7);
    GLD16(&Kg[(size_t)kg * 64 + cb * 8], (char*)KP + q * 1024);
  }
  // --- async stage V: 64 rows x 192 shorts = 24 chunks ---
  #pragma unroll
  for (int s = 0; s < 6; ++s) {
    int q = s * 4 + wave;
    int L = q * 64 + lane;
    int row = L / 24;
    int c24 = L - row * 24;
    int cb = (c24 & ~7) | ((c24 & 7) ^ (row & 7));
    GLD16(&Vb[(size_t)row * 2048 + kb + cb * 8], (char*)Vt + q * 1024);
  }
  const unsigned short* Qg = Q + ((size_t)bh * Tt + t0 + q0) * 64;
  s16x8 aq0 = *(const s16x8*)&Qg[ln * 64 + qd * 8];
  s16x8 aq1 = *(const s16x8*)&Qg[ln * 64 + 32 + qd * 8];
  __syncthreads();   // vmcnt drain: staging + Q complete

  int swk0 = ((qd) ^ (ln & 7)) * 8;        // stored chunk of global chunk qd
  int swk1 = ((qd + 4) ^ (ln & 7)) * 8;    // stored chunk of global chunk 4+qd
  f32x4 sf[12];
  __builtin_amdgcn_s_setprio(1);
  #pragma unroll
  for (int nt = 0; nt < 12; ++nt) {
    const unsigned short* kr = &KP[(nt * 16 + ln) * 64];
    s16x8 b0 = *(const s16x8*)&kr[swk0];
    s16x8 b1 = *(const s16x8*)&kr[swk1];
    f32x4 a = {0.f, 0.f, 0.f, 0.f};
    a = __builtin_amdgcn_mfma_f32_16x16x32_bf16(aq0, b0, a, 0, 0, 0);
    a = __builtin_amdgcn_mfma_f32_16x16x32_bf16(aq1, b1, a, 0, 0, 0);
    sf[nt] = a;
  }
  __builtin_amdgcn_s_setprio(0);
  __syncthreads();  // K reads done; safe to overwrite KP with P

  unsigned short* Pl = KP;
  int ok0 = (t0 < 128) ? (128 - t0) : 0;
  #pragma unroll
  for (int r = 0; r < 4; ++r) {
    int lq = q0 + qd * 4 + r;
    float mx = -INFINITY;
    #pragma unroll
    for (int nt = 0; nt < 12; ++nt) {
      int kk = nt * 16 + ln;
      bool valid = (kk > lq) && (kk <= lq + 128) && (kk >= ok0);
      float s = valid ? sf[nt][r] * 0.125f : -INFINITY;
      sf[nt][r] = s;
      mx = fmaxf(mx, s);
    }
    mx = fmaxf(mx, __shfl_xor(mx, 1, 64));
    mx = fmaxf(mx, __shfl_xor(mx, 2, 64));
    mx = fmaxf(mx, __shfl_xor(mx, 4, 64));
    mx = fmaxf(mx, __shfl_xor(mx, 8, 64));
    float sum = 0.f;
    #pragma unroll
    for (int nt = 0; nt < 12; ++nt) {
      float e = __expf(sf[nt][r] - mx);
      sf[nt][r] = e;
      sum += e;
    }
    sum += __shfl_xor(sum, 1, 64);
    sum += __shfl_xor(sum, 2, 64);
    sum += __shfl_xor(sum, 4, 64);
    sum += __shfl_xor(sum, 8, 64);
    float inv = 1.0f / sum;
    #pragma unroll
    for (int nt = 0; nt < 12; ++nt) {
      int kk = nt * 16 + ln;
      int c = kk >> 3;
      int swc = (c & ~7) | ((c & 7) ^ (lq & 7));
      Pl[lq * 192 + swc * 8 + (kk & 7)] = f2bf(sf[nt][r] * inv);
    }
  }
  // no barrier: P rows + O-stage region are wave-private, Vt stable

  f32x4 oa[4] = {f32x4{0,0,0,0}, f32x4{0,0,0,0}, f32x4{0,0,0,0}, f32x4{0,0,0,0}};
  __builtin_amdgcn_s_setprio(1);
  #pragma unroll
  for (int s = 0; s < 6; ++s) {
    int c = s * 4 + qd;                           // global chunk 0..23
    int swc = (c & ~7) | ((c & 7) ^ (ln & 7));    // row&7 == ln&7 for P and V
    s16x8 ap = *(const s16x8*)&Pl[(q0 + ln) * 192 + swc * 8];
    #pragma unroll
    for (int nt = 0; nt < 4; ++nt) {
      s16x8 bv = *(const s16x8*)&Vt[(nt * 16 + ln) * 192 + swc * 8];
      oa[nt] = __builtin_amdgcn_mfma_f32_16x16x32_bf16(ap, bv, oa[nt], 0, 0, 0);
    }
  }
  __builtin_amdgcn_s_setprio(0);

  unsigned short* Ow = KP + q0 * 192;   // overlay this wave's P rows
  #pragma unroll
  for (int ni = 0; ni < 4; ++ni)
    #pragma unroll
    for (int r = 0; r < 4; ++r)
      Ow[(qd * 4 + r) * 72 + ni * 16 + ln] = f2bf(oa[ni][r]);
  int b = bh >> 3, h = bh & 7;
  #pragma unroll
  for (int i = 0; i < 2; ++i) {
    int idx = i * 64 + lane;
    int rr = idx >> 3, cc = (idx & 7) * 8;
    *(u16x8*)&AO[((size_t)(b * Tt + t0 + q0 + rr) * Hh + h) * 64 + cc] =
        *(const u16x8*)&Ow[rr * 72 + cc];
  }
}

// ------- output GEMM v2 (128x64 tile, dbuf LDS): AO @ W_o -> f32 ------------
// grid (32, 8) = 256 blocks; 4 waves stacked, each 32x64 out (acc[2][4]).
__global__ __launch_bounds__(256) void out_gemm(
    const unsigned short* __restrict__ Am,  // (4096,512) bf16
    const unsigned short* __restrict__ WT,  // (512,512) bf16 [n][k]
    float* __restrict__ Out) {              // (4096,512) f32
  // 48 KB: buffer b at S + b*12288 (A 128x64 = 8192 shorts, B 64x64 = 4096)
  __shared__ alignas(16) unsigned short S[24576];
  int tid = threadIdx.x;
  int wave = tid >> 6, lane = tid & 63;
  int ln = lane & 15, qd = lane >> 4;
  int id = (int)blockIdx.x + 32 * (int)blockIdx.y;   // 0..255
  int swb = (id & 7) * 32 + (id >> 3);               // 32/XCD = one n-column
  int m0 = (swb & 31) * 128, n0 = (swb >> 5) * 64;

  f32x4 acc[2][4];
  #pragma unroll
  for (int mi = 0; mi < 2; ++mi)
    #pragma unroll
    for (int ni = 0; ni < 4; ++ni) acc[mi][ni] = f32x4{0.f, 0.f, 0.f, 0.f};

  auto stage = [&](int k0, int buf) {
    char* Apt = (char*)(S + buf * 12288);
    char* Bpt = (char*)(S + buf * 12288 + 8192);
    #pragma unroll
    for (int s = 0; s < 4; ++s) {    // A: 16 chunks of 1 KB
      int q = s * 4 + wave;
      int L = q * 64 + lane;
      int row = L >> 3;
      int cb = (L & 7) ^ (row & 7);
      GLD16(&Am[(size_t)(m0 + row) * 512 + k0 + cb * 8], Apt + q * 1024);
    }
    #pragma unroll
    for (int s = 0; s < 2; ++s) {    // B: 8 chunks
      int q = s * 4 + wave;
      int L = q * 64 + lane;
      int row = L >> 3;
      int cb = (L & 7) ^ (row & 7);
      GLD16(&WT[(size_t)(n0 + row) * 512 + k0 + cb * 8], Bpt + q * 1024);
    }
  };

  stage(0, 0);
  __syncthreads();
  for (int it = 0; it < 8; ++it) {
    int cur = it & 1;
    if (it < 7) stage((it + 1) * 64, cur ^ 1);
    const char* Al = (const char*)(S + cur * 12288);
    const char* Bl = (const char*)(S + cur * 12288 + 8192);
    #pragma unroll
    for (int half = 0; half < 2; ++half) {
      s16x8 af[2], bfr[4];
      #pragma unroll
      for (int mi = 0; mi < 2; ++mi) {
        int ar = wave * 32 + mi * 16 + ln;
        int cbp = (qd + half * 4) ^ (ar & 7);
        af[mi] = *(const s16x8*)(Al + ar * 128 + cbp * 16);
      }
      #pragma unroll
      for (int ni = 0; ni < 4; ++ni) {
        int br = ni * 16 + ln;
        int cbp = (qd + half * 4) ^ (br & 7);
        bfr[ni] = *(const s16x8*)(Bl + br * 128 + cbp * 16);
      }
      #pragma unroll
      for (int mi = 0; mi < 2; ++mi)
        #pragma unroll
        for (int ni = 0; ni < 4; ++ni)
          acc[mi][ni] = __builtin_amdgcn_mfma_f32_16x16x32_bf16(
              af[mi], bfr[ni], acc[mi][ni], 0, 0, 0);
    }
    __syncthreads();
  }

  #pragma unroll
  for (int mi = 0; mi < 2; ++mi)
    #pragma unroll
    for (int r = 0; r < 4; ++r) {
      int row = m0 + wave * 32 + mi * 16 + qd * 4 + r;
      #pragma unroll
      for (int ni = 0; ni < 4; ++ni)
        Out[(size_t)row * 512 + n0 + ni * 16 + ln] = acc[mi][ni][r];
    }
}

extern "C" void kernel_launch(void* const* d_in, const int* in_sizes, int n_in,
                              void* d_out, int out_size, void* d_ws,
                              size_t ws_size, hipStream_t stream) {
  const float* h   = (const float*)d_in[0];
  const float* rc  = (const float*)d_in[1];
  const float* rs  = (const float*)d_in[2];
  const float* Wq  = (const float*)d_in[3];
  const float* Wk  = (const float*)d_in[4];
  const float* Wv  = (const float*)d_in[5];
  const float* Wo  = (const float*)d_in[6];
  const float* qnw = (const float*)d_in[7];
  const float* knw = (const float*)d_in[8];

  unsigned short* ws    = (unsigned short*)d_ws;
  unsigned short* WTall = ws;                       // 1536*512 (q,k,v contiguous)
  unsigned short* WTo   = WTall + 1536 * 512;       // 512*512
  unsigned short* Hb    = WTo + 512 * 512;          // 4096*512 bf16
  unsigned short* Qw    = Hb + 2097152;             // (B,H,T,C)
  unsigned short* Kw    = Qw + 2097152;             // (B,H,T,C)
  unsigned short* Vw    = Kw + 2097152;             // (B,H,C,T)
  unsigned short* AOw   = Vw + 2097152;             // (B,T,H,C)

  prep_all<<<dim3(8, 8, 5), 256, 0, stream>>>(Wq, Wk, Wv, Wo, WTall, h, Hb);

  qkv_fused<<<dim3(32, 12), 256, 0, stream>>>(Hb, WTall, qnw, knw, rc, rs,
                                              Qw, Kw, Vw);

  attn_mfma<<<dim3(32, 16), 256, 0, stream>>>(Qw, Kw, Vw, AOw);

  out_gemm<<<dim3(32, 8), 256, 0, stream>>>(AOw, WTo, (float*)d_out);
}

// Round 3
// 108.239 us; speedup vs baseline: 1.0219x; 1.0219x over previous
//
#include <hip/hip_runtime.h>
#include <hip/hip_bf16.h>
#include <cmath>

#define Tt 2048
#define Hh 8

using u16x8 = __attribute__((ext_vector_type(8))) unsigned short;
using s16x8 = __attribute__((ext_vector_type(8))) short;
using f32x4 = __attribute__((ext_vector_type(4))) float;

__device__ __forceinline__ unsigned short f2bf(float f) {
  __hip_bfloat16 b = __float2bfloat16(f);
  return *reinterpret_cast<unsigned short*>(&b);
}

// async global->LDS, 16B/lane; dest = uniform base + lane*16 (m97/m104)
#define GLD16(gp, lp)                                                        \
  __builtin_amdgcn_global_load_lds(                                          \
      (const __attribute__((address_space(1))) unsigned int*)(gp),           \
      (__attribute__((address_space(3))) unsigned int*)(lp), 16, 0, 0)

// ---- prep: z<4 -> transpose+cvt weight z into WTall; z==4 -> cvt h ---------
__global__ __launch_bounds__(256) void prep_all(
    const float* __restrict__ s0, const float* __restrict__ s1,
    const float* __restrict__ s2, const float* __restrict__ s3,
    unsigned short* __restrict__ d,
    const float* __restrict__ hsrc, unsigned short* __restrict__ hdst) {
  int tid = threadIdx.x;
  if (blockIdx.z == 4) {
    int gid = ((int)blockIdx.y * 8 + blockIdx.x) * 256 + tid;  // 0..16383
    #pragma unroll
    for (int s = 0; s < 16; ++s) {
      size_t i = ((size_t)s * 16384 + gid) * 8;
      const float4* g = (const float4*)&hsrc[i];
      float4 f0 = g[0], f1 = g[1];
      u16x8 o = {f2bf(f0.x), f2bf(f0.y), f2bf(f0.z), f2bf(f0.w),
                 f2bf(f1.x), f2bf(f1.y), f2bf(f1.z), f2bf(f1.w)};
      *(u16x8*)&hdst[i] = o;
    }
    return;
  }
  __shared__ unsigned short tile[64 * 65];
  const float* srcs[4] = {s0, s1, s2, s3};
  const float* src = srcs[blockIdx.z];
  unsigned short* dst = d + (size_t)blockIdx.z * 512 * 512;
  int n0 = blockIdx.x * 64, k0 = blockIdx.y * 64;
  int tx = tid & 63, ty = tid >> 6;
  #pragma unroll
  for (int i = 0; i < 16; ++i) {
    int k = ty * 16 + i;
    tile[k * 65 + tx] = f2bf(src[(k0 + k) * 512 + n0 + tx]);
  }
  __syncthreads();
  #pragma unroll
  for (int i = 0; i < 16; ++i) {
    int n = ty * 16 + i;
    dst[(n0 + n) * 512 + k0 + tx] = tile[tx * 65 + n];
  }
}

// -------- fused QKV GEMM (128x64 tile, dbuf LDS, 1 barrier/K-iter) ----------
// grid (32, 24): y = gh -> mat = gh>>3 (Q/K/V), head = gh&7.
// Q,K out: (B,H,T,C). V out: (B,H,C,T).
__global__ __launch_bounds__(256) void qkv_fused(
    const unsigned short* __restrict__ Hb,     // (4096,512) bf16
    const unsigned short* __restrict__ WTall,  // (1536,512) bf16 [n][k]
    const float* __restrict__ qnw, const float* __restrict__ knw,
    const float* __restrict__ rcos, const float* __restrict__ rsin,
    unsigned short* __restrict__ Qw, unsigned short* __restrict__ Kw,
    unsigned short* __restrict__ Vw) {
  // 48 KB: buffer b at S + b*12288 (A 128x64 = 8192 shorts, B 64x64 = 4096)
  __shared__ alignas(16) unsigned short S[24576];
  int tid = threadIdx.x;
  int wave = tid >> 6, lane = tid & 63;
  int ln = lane & 15, qd = lane >> 4;
  // XCD-aware bijective swizzle: 768 blocks, 96/XCD = 3 full gh columns
  int id = (int)blockIdx.x + 32 * (int)blockIdx.y;
  int sw = (id & 7) * 96 + (id >> 3);
  int m0 = (sw & 31) * 128;
  int gh = sw >> 5;
  int n0 = gh * 64;

  f32x4 acc[2][4];
  #pragma unroll
  for (int mi = 0; mi < 2; ++mi)
    #pragma unroll
    for (int ni = 0; ni < 4; ++ni) acc[mi][ni] = f32x4{0.f, 0.f, 0.f, 0.f};

  auto stage = [&](int k0, int buf) {
    char* Apt = (char*)(S + buf * 12288);
    char* Bpt = (char*)(S + buf * 12288 + 8192);
    #pragma unroll
    for (int s = 0; s < 4; ++s) {    // A: 16 chunks of 1 KB
      int q = s * 4 + wave;
      int L = q * 64 + lane;
      int row = L >> 3;
      int cb = (L & 7) ^ (row & 7);
      GLD16(&Hb[(size_t)(m0 + row) * 512 + k0 + cb * 8], Apt + q * 1024);
    }
    #pragma unroll
    for (int s = 0; s < 2; ++s) {    // B: 8 chunks
      int q = s * 4 + wave;
      int L = q * 64 + lane;
      int row = L >> 3;
      int cb = (L & 7) ^ (row & 7);
      GLD16(&WTall[(size_t)(n0 + row) * 512 + k0 + cb * 8], Bpt + q * 1024);
    }
  };

  stage(0, 0);
  __syncthreads();
  for (int it = 0; it < 8; ++it) {
    int cur = it & 1;
    if (it < 7) stage((it + 1) * 64, cur ^ 1);
    const char* Al = (const char*)(S + cur * 12288);
    const char* Bl = (const char*)(S + cur * 12288 + 8192);
    #pragma unroll
    for (int half = 0; half < 2; ++half) {
      s16x8 af[2], bfr[4];
      #pragma unroll
      for (int mi = 0; mi < 2; ++mi) {
        int ar = wave * 32 + mi * 16 + ln;
        int cbp = (qd + half * 4) ^ (ar & 7);
        af[mi] = *(const s16x8*)(Al + ar * 128 + cbp * 16);
      }
      #pragma unroll
      for (int ni = 0; ni < 4; ++ni) {
        int br = ni * 16 + ln;
        int cbp = (qd + half * 4) ^ (br & 7);
        bfr[ni] = *(const s16x8*)(Bl + br * 128 + cbp * 16);
      }
      #pragma unroll
      for (int mi = 0; mi < 2; ++mi)
        #pragma unroll
        for (int ni = 0; ni < 4; ++ni)
          acc[mi][ni] = __builtin_amdgcn_mfma_f32_16x16x32_bf16(
              af[mi], bfr[ni], acc[mi][ni], 0, 0, 0);
    }
    __syncthreads();   // single drain: loads for it+1 had full MFMA phase
  }

  int mat = gh >> 3, head = gh & 7;
  const float* nw = (mat == 0) ? qnw : knw;
  bool do_rope = (mat < 2);
  int mrow0 = m0 + wave * 32;
  int b = mrow0 >> 11, tb = mrow0 & (Tt - 1);

  #pragma unroll
  for (int mi = 0; mi < 2; ++mi) {
    float vals[4][4];
    #pragma unroll
    for (int ni = 0; ni < 4; ++ni)
      #pragma unroll
      for (int r = 0; r < 4; ++r) vals[ni][r] = acc[mi][ni][r];

    if (do_rope) {
      #pragma unroll
      for (int r = 0; r < 4; ++r) {
        float ss = 0.f;
        #pragma unroll
        for (int ni = 0; ni < 4; ++ni) ss += vals[ni][r] * vals[ni][r];
        ss += __shfl_xor(ss, 1, 64);
        ss += __shfl_xor(ss, 2, 64);
        ss += __shfl_xor(ss, 4, 64);
        ss += __shfl_xor(ss, 8, 64);
        float nrm = rsqrtf(ss * (1.0f / 64.0f) + 1e-6f);
        #pragma unroll
        for (int ni = 0; ni < 4; ++ni) vals[ni][r] *= nrm;
      }
      #pragma unroll
      for (int ni = 0; ni < 4; ++ni) {
        float w = nw[ni * 16 + ln];
        #pragma unroll
        for (int r = 0; r < 4; ++r) vals[ni][r] *= w;
      }
      float res[4][4];
      #pragma unroll
      for (int r = 0; r < 4; ++r) {
        int t = tb + mi * 16 + qd * 4 + r;
        #pragma unroll
        for (int ni = 0; ni < 4; ++ni) {
          int c = ni * 16 + ln;
          float cs = rcos[t * 64 + c];
          float sn = rsin[t * 64 + c];
          float part = vals[ni ^ 2][r];
          float rot = (ni < 2) ? -part : part;
          res[ni][r] = vals[ni][r] * cs + rot * sn;
        }
      }
      #pragma unroll
      for (int ni = 0; ni < 4; ++ni)
        #pragma unroll
        for (int r = 0; r < 4; ++r) vals[ni][r] = res[ni][r];
    }

    if (mat < 2) {   // [t_local 32][c 64] pad 72, wave-private
      unsigned short* Wl = S + wave * 2304;
      #pragma unroll
      for (int ni = 0; ni < 4; ++ni)
        #pragma unroll
        for (int r = 0; r < 4; ++r)
          Wl[(mi * 16 + qd * 4 + r) * 72 + ni * 16 + ln] = f2bf(vals[ni][r]);
    } else {         // V: [c 64][t_local 32] pad 40
      unsigned short* Wl = S + wave * 2560;
      #pragma unroll
      for (int ni = 0; ni < 4; ++ni)
        #pragma unroll
        for (int r = 0; r < 4; ++r)
          Wl[(ni * 16 + ln) * 40 + mi * 16 + qd * 4 + r] = f2bf(vals[ni][r]);
    }
  }

  if (mat < 2) {
    unsigned short* Wl = S + wave * 2304;
    unsigned short* Og =
        ((mat == 0) ? Qw : Kw) + (((size_t)b * Hh + head) * Tt + tb) * 64;
    #pragma unroll
    for (int i = 0; i < 4; ++i) {    // 32 rows x 64 = 256 chunks
      int idx = i * 64 + lane;
      int rr = idx >> 3, cc = (idx & 7) * 8;
      *(u16x8*)&Og[rr * 64 + cc] = *(const u16x8*)&Wl[rr * 72 + cc];
    }
  } else {
    unsigned short* Wl = S + wave * 2560;
    unsigned short* Og = Vw + ((size_t)b * Hh + head) * 64 * 2048 + tb;
    #pragma unroll
    for (int i = 0; i < 4; ++i) {    // 64 c-rows x 32 t = 256 chunks
      int idx = i * 64 + lane;
      int rr = idx >> 2, cc = (idx & 3) * 8;
      *(u16x8*)&Og[(size_t)rr * 2048 + cc] = *(const u16x8*)&Wl[rr * 40 + cc];
    }
  }
}

// ---------- MFMA sliding-window attention: 64 queries / block ---------------
// Q,K: (B,H,T,C); V: (B,H,C,T). AO: (B,T,H,C). 24 KB LDS (K tile -> P -> O).
// v3: V staging DROPPED (guide m169: L2-resident V staging is pure overhead).
// PV B-fragments read directly from global V (t-contiguous in (C,T) layout).
__global__ __launch_bounds__(256) void attn_mfma(
    const unsigned short* __restrict__ Q,
    const unsigned short* __restrict__ K,
    const unsigned short* __restrict__ Vg,
    unsigned short* __restrict__ AO) {
  __shared__ alignas(16) unsigned short KP[192 * 64];  // K tile; then P[64][192]
  int tid = threadIdx.x;
  int wave = tid >> 6, lane = tid & 63;
  int ln = lane & 15, qd = lane >> 4;
  int id = (int)blockIdx.x + 32 * (int)blockIdx.y;
  int swb = (id & 7) * 64 + (id >> 3);
  int t0 = (swb & 31) * 64, bh = swb >> 5;
  int kb = t0 - 128;
  int q0 = wave * 16;

  const unsigned short* Kg = K + (size_t)bh * Tt * 64;
  const unsigned short* Vb = Vg + (size_t)bh * 64 * 2048;

  // --- async stage K: 192 rows x 64 shorts = 24 chunks of 1 KB ---
  #pragma unroll
  for (int s = 0; s < 6; ++s) {
    int q = s * 4 + wave;
    int L = q * 64 + lane;
    int row = L >> 3;
    int kg = kb + row; if (kg < 0) kg = 0;   // garbage row, masked by P=0
    int cb = (L & 7) ^ (row & 7);
    GLD16(&Kg[(size_t)kg * 64 + cb * 8], (char*)KP + q * 1024);
  }
  const unsigned short* Qg = Q + ((size_t)bh * Tt + t0 + q0) * 64;
  s16x8 aq0 = *(const s16x8*)&Qg[ln * 64 + qd * 8];
  s16x8 aq1 = *(const s16x8*)&Qg[ln * 64 + 32 + qd * 8];
  __syncthreads();   // vmcnt drain: K staging complete

  int swk0 = ((qd) ^ (ln & 7)) * 8;        // stored chunk of global chunk qd
  int swk1 = ((qd + 4) ^ (ln & 7)) * 8;    // stored chunk of global chunk 4+qd
  f32x4 sf[12];
  __builtin_amdgcn_s_setprio(1);
  #pragma unroll
  for (int nt = 0; nt < 12; ++nt) {
    const unsigned short* kr = &KP[(nt * 16 + ln) * 64];
    s16x8 b0 = *(const s16x8*)&kr[swk0];
    s16x8 b1 = *(const s16x8*)&kr[swk1];
    f32x4 a = {0.f, 0.f, 0.f, 0.f};
    a = __builtin_amdgcn_mfma_f32_16x16x32_bf16(aq0, b0, a, 0, 0, 0);
    a = __builtin_amdgcn_mfma_f32_16x16x32_bf16(aq1, b1, a, 0, 0, 0);
    sf[nt] = a;
  }
  __builtin_amdgcn_s_setprio(0);
  __syncthreads();  // K reads done; safe to overwrite KP with P

  unsigned short* Pl = KP;
  int ok0 = (t0 < 128) ? (128 - t0) : 0;
  #pragma unroll
  for (int r = 0; r < 4; ++r) {
    int lq = q0 + qd * 4 + r;
    float mx = -INFINITY;
    #pragma unroll
    for (int nt = 0; nt < 12; ++nt) {
      int kk = nt * 16 + ln;
      bool valid = (kk > lq) && (kk <= lq + 128) && (kk >= ok0);
      float s = valid ? sf[nt][r] * 0.125f : -INFINITY;
      sf[nt][r] = s;
      mx = fmaxf(mx, s);
    }
    mx = fmaxf(mx, __shfl_xor(mx, 1, 64));
    mx = fmaxf(mx, __shfl_xor(mx, 2, 64));
    mx = fmaxf(mx, __shfl_xor(mx, 4, 64));
    mx = fmaxf(mx, __shfl_xor(mx, 8, 64));
    float sum = 0.f;
    #pragma unroll
    for (int nt = 0; nt < 12; ++nt) {
      float e = __expf(sf[nt][r] - mx);
      sf[nt][r] = e;
      sum += e;
    }
    sum += __shfl_xor(sum, 1, 64);
    sum += __shfl_xor(sum, 2, 64);
    sum += __shfl_xor(sum, 4, 64);
    sum += __shfl_xor(sum, 8, 64);
    float inv = 1.0f / sum;
    #pragma unroll
    for (int nt = 0; nt < 12; ++nt) {
      int kk = nt * 16 + ln;
      int c = kk >> 3;
      int swc = (c & ~7) | ((c & 7) ^ (lq & 7));
      Pl[lq * 192 + swc * 8 + (kk & 7)] = f2bf(sf[nt][r] * inv);
    }
  }
  // no barrier: P rows + O-stage region are wave-private

  // PV: A = P rows from LDS; B = V fragments DIRECT from global (L2-hot).
  // kb + s*32 + qd*8 can be <0 only for t0=0 (reads tail of Kw buffer:
  // finite bf16 garbage, multiplied by P=0).
  f32x4 oa[4] = {f32x4{0,0,0,0}, f32x4{0,0,0,0}, f32x4{0,0,0,0}, f32x4{0,0,0,0}};
  __builtin_amdgcn_s_setprio(1);
  #pragma unroll
  for (int s = 0; s < 6; ++s) {
    int c = s * 4 + qd;                           // k-chunk 0..23
    int swc = (c & ~7) | ((c & 7) ^ (ln & 7));    // P stored-chunk for row q0+ln
    s16x8 ap = *(const s16x8*)&Pl[(q0 + ln) * 192 + swc * 8];
    #pragma unroll
    for (int nt = 0; nt < 4; ++nt) {
      s16x8 bv = *(const s16x8*)&Vb[(size_t)(nt * 16 + ln) * 2048 + kb + s * 32 + qd * 8];
      oa[nt] = __builtin_amdgcn_mfma_f32_16x16x32_bf16(ap, bv, oa[nt], 0, 0, 0);
    }
  }
  __builtin_amdgcn_s_setprio(0);

  unsigned short* Ow = KP + q0 * 192;   // overlay this wave's P rows
  #pragma unroll
  for (int ni = 0; ni < 4; ++ni)
    #pragma unroll
    for (int r = 0; r < 4; ++r)
      Ow[(qd * 4 + r) * 72 + ni * 16 + ln] = f2bf(oa[ni][r]);
  int b = bh >> 3, h = bh & 7;
  #pragma unroll
  for (int i = 0; i < 2; ++i) {
    int idx = i * 64 + lane;
    int rr = idx >> 3, cc = (idx & 7) * 8;
    *(u16x8*)&AO[((size_t)(b * Tt + t0 + q0 + rr) * Hh + h) * 64 + cc] =
        *(const u16x8*)&Ow[rr * 72 + cc];
  }
}

// ------------- output GEMM (64x64 tile, dbuf LDS): AO @ W_o -> f32 ----------
__global__ __launch_bounds__(256) void out_gemm(
    const unsigned short* __restrict__ Am,  // (4096,512) bf16
    const unsigned short* __restrict__ WT,  // (512,512) bf16 [n][k]
    float* __restrict__ Out) {              // (4096,512) f32
  // 32 KB: buffer b at S + b*8192 (A 64x64 = 4096 shorts, B same)
  __shared__ alignas(16) unsigned short S[16384];
  int tid = threadIdx.x;
  int wave = tid >> 6, lane = tid & 63;
  int ln = lane & 15, qd = lane >> 4;
  int wm = wave >> 1, wn = wave & 1;
  int id = (int)blockIdx.x + 64 * (int)blockIdx.y;
  int swb = (id & 7) * 64 + (id >> 3);
  int m0 = (swb & 63) * 64, n0 = (swb >> 6) * 64;

  f32x4 acc[2][2];
  #pragma unroll
  for (int mi = 0; mi < 2; ++mi)
    #pragma unroll
    for (int ni = 0; ni < 2; ++ni) acc[mi][ni] = f32x4{0.f, 0.f, 0.f, 0.f};

  auto stage = [&](int k0, int buf) {
    char* Apt = (char*)(S + buf * 8192);
    char* Bpt = (char*)(S + buf * 8192 + 4096);
    #pragma unroll
    for (int s = 0; s < 2; ++s) {
      int q = s * 4 + wave;
      int L = q * 64 + lane;
      int row = L >> 3;
      int cb = (L & 7) ^ (row & 7);
      GLD16(&Am[(size_t)(m0 + row) * 512 + k0 + cb * 8], Apt + q * 1024);
      GLD16(&WT[(size_t)(n0 + row) * 512 + k0 + cb * 8], Bpt + q * 1024);
    }
  };

  stage(0, 0);
  __syncthreads();
  for (int it = 0; it < 8; ++it) {
    int cur = it & 1;
    if (it < 7) stage((it + 1) * 64, cur ^ 1);
    const char* Al = (const char*)(S + cur * 8192);
    const char* Bl = (const char*)(S + cur * 8192 + 4096);
    #pragma unroll
    for (int half = 0; half < 2; ++half) {
      s16x8 af[2], bfr[2];
      #pragma unroll
      for (int mi = 0; mi < 2; ++mi) {
        int ar = wm * 32 + mi * 16 + ln;
        int cbp = (qd + half * 4) ^ (ar & 7);
        af[mi] = *(const s16x8*)(Al + ar * 128 + cbp * 16);
      }
      #pragma unroll
      for (int ni = 0; ni < 2; ++ni) {
        int br = wn * 32 + ni * 16 + ln;
        int cbp = (qd + half * 4) ^ (br & 7);
        bfr[ni] = *(const s16x8*)(Bl + br * 128 + cbp * 16);
      }
      #pragma unroll
      for (int mi = 0; mi < 2; ++mi)
        #pragma unroll
        for (int ni = 0; ni < 2; ++ni)
          acc[mi][ni] = __builtin_amdgcn_mfma_f32_16x16x32_bf16(
              af[mi], bfr[ni], acc[mi][ni], 0, 0, 0);
    }
    __syncthreads();
  }

  #pragma unroll
  for (int mi = 0; mi < 2; ++mi)
    #pragma unroll
    for (int r = 0; r < 4; ++r) {
      int row = m0 + wm * 32 + mi * 16 + qd * 4 + r;
      #pragma unroll
      for (int ni = 0; ni < 2; ++ni)
        Out[(size_t)row * 512 + n0 + wn * 32 + ni * 16 + ln] = acc[mi][ni][r];
    }
}

extern "C" void kernel_launch(void* const* d_in, const int* in_sizes, int n_in,
                              void* d_out, int out_size, void* d_ws,
                              size_t ws_size, hipStream_t stream) {
  const float* h   = (const float*)d_in[0];
  const float* rc  = (const float*)d_in[1];
  const float* rs  = (const float*)d_in[2];
  const float* Wq  = (const float*)d_in[3];
  const float* Wk  = (const float*)d_in[4];
  const float* Wv  = (const float*)d_in[5];
  const float* Wo  = (const float*)d_in[6];
  const float* qnw = (const float*)d_in[7];
  const float* knw = (const float*)d_in[8];

  unsigned short* ws    = (unsigned short*)d_ws;
  unsigned short* WTall = ws;                       // 1536*512 (q,k,v contiguous)
  unsigned short* WTo   = WTall + 1536 * 512;       // 512*512
  unsigned short* Hb    = WTo + 512 * 512;          // 4096*512 bf16
  unsigned short* Qw    = Hb + 2097152;             // (B,H,T,C)
  unsigned short* Kw    = Qw + 2097152;             // (B,H,T,C)
  unsigned short* Vw    = Kw + 2097152;             // (B,H,C,T)
  unsigned short* AOw   = Vw + 2097152;             // (B,T,H,C)

  prep_all<<<dim3(8, 8, 5), 256, 0, stream>>>(Wq, Wk, Wv, Wo, WTall, h, Hb);

  qkv_fused<<<dim3(32, 24), 256, 0, stream>>>(Hb, WTall, qnw, knw, rc, rs,
                                              Qw, Kw, Vw);

  attn_mfma<<<dim3(32, 16), 256, 0, stream>>>(Qw, Kw, Vw, AOw);

  out_gemm<<<dim3(64, 8), 256, 0, stream>>>(AOw, WTo, (float*)d_out);
}

// Round 5
// 106.451 us; speedup vs baseline: 1.0390x; 1.0168x over previous
//
#include <hip/hip_runtime.h>
#include <hip/hip_bf16.h>
#include <cmath>

#define Tt 2048
#define Hh 8

using u16x8 = __attribute__((ext_vector_type(8))) unsigned short;
using s16x8 = __attribute__((ext_vector_type(8))) short;
using f32x4 = __attribute__((ext_vector_type(4))) float;

__device__ __forceinline__ unsigned short f2bf(float f) {
  __hip_bfloat16 b = __float2bfloat16(f);
  return *reinterpret_cast<unsigned short*>(&b);
}

// async global->LDS, 16B/lane; dest = uniform base + lane*16 (m97/m104)
#define GLD16(gp, lp)                                                        \
  __builtin_amdgcn_global_load_lds(                                          \
      (const __attribute__((address_space(1))) unsigned int*)(gp),           \
      (__attribute__((address_space(3))) unsigned int*)(lp), 16, 0, 0)

// ---- prep: z<4 -> transpose+cvt weight z into WTall; z==4 -> cvt h ---------
__global__ __launch_bounds__(256) void prep_all(
    const float* __restrict__ s0, const float* __restrict__ s1,
    const float* __restrict__ s2, const float* __restrict__ s3,
    unsigned short* __restrict__ d,
    const float* __restrict__ hsrc, unsigned short* __restrict__ hdst) {
  int tid = threadIdx.x;
  if (blockIdx.z == 4) {
    int gid = ((int)blockIdx.y * 8 + blockIdx.x) * 256 + tid;  // 0..16383
    #pragma unroll
    for (int s = 0; s < 16; ++s) {
      size_t i = ((size_t)s * 16384 + gid) * 8;
      const float4* g = (const float4*)&hsrc[i];
      float4 f0 = g[0], f1 = g[1];
      u16x8 o = {f2bf(f0.x), f2bf(f0.y), f2bf(f0.z), f2bf(f0.w),
                 f2bf(f1.x), f2bf(f1.y), f2bf(f1.z), f2bf(f1.w)};
      *(u16x8*)&hdst[i] = o;
    }
    return;
  }
  __shared__ unsigned short tile[64 * 65];
  const float* srcs[4] = {s0, s1, s2, s3};
  const float* src = srcs[blockIdx.z];
  unsigned short* dst = d + (size_t)blockIdx.z * 512 * 512;
  int n0 = blockIdx.x * 64, k0 = blockIdx.y * 64;
  int tx = tid & 63, ty = tid >> 6;
  #pragma unroll
  for (int i = 0; i < 16; ++i) {
    int k = ty * 16 + i;
    tile[k * 65 + tx] = f2bf(src[(k0 + k) * 512 + n0 + tx]);
  }
  __syncthreads();
  #pragma unroll
  for (int i = 0; i < 16; ++i) {
    int n = ty * 16 + i;
    dst[(n0 + n) * 512 + k0 + tx] = tile[tx * 65 + n];
  }
}

// -------- fused QKV GEMM (128x64 tile, dbuf LDS, 1 barrier/K-iter) ----------
// grid (32, 24): XCD-swizzled. y = gh -> mat = gh>>3 (Q/K/V), head = gh&7.
// Q,K out: (B,H,T,C). V out: (B,H,C,T).
__global__ __launch_bounds__(256) void qkv_fused(
    const unsigned short* __restrict__ Hb,     // (4096,512) bf16
    const unsigned short* __restrict__ WTall,  // (1536,512) bf16 [n][k]
    const float* __restrict__ qnw, const float* __restrict__ knw,
    const float* __restrict__ rcos, const float* __restrict__ rsin,
    unsigned short* __restrict__ Qw, unsigned short* __restrict__ Kw,
    unsigned short* __restrict__ Vw) {
  // 48 KB: buffer b at S + b*12288 (A 128x64 = 8192 shorts, B 64x64 = 4096)
  __shared__ alignas(16) unsigned short S[24576];
  int tid = threadIdx.x;
  int wave = tid >> 6, lane = tid & 63;
  int ln = lane & 15, qd = lane >> 4;
  // XCD-aware bijective swizzle: 768 blocks, 96/XCD = 3 full gh columns
  int id = (int)blockIdx.x + 32 * (int)blockIdx.y;
  int sw = (id & 7) * 96 + (id >> 3);
  int m0 = (sw & 31) * 128;
  int gh = sw >> 5;
  int n0 = gh * 64;

  f32x4 acc[2][4];
  #pragma unroll
  for (int mi = 0; mi < 2; ++mi)
    #pragma unroll
    for (int ni = 0; ni < 4; ++ni) acc[mi][ni] = f32x4{0.f, 0.f, 0.f, 0.f};

  auto stage = [&](int k0, int buf) {
    char* Apt = (char*)(S + buf * 12288);
    char* Bpt = (char*)(S + buf * 12288 + 8192);
    #pragma unroll
    for (int s = 0; s < 4; ++s) {    // A: 16 chunks of 1 KB
      int q = s * 4 + wave;
      int L = q * 64 + lane;
      int row = L >> 3;
      int cb = (L & 7) ^ (row & 7);
      GLD16(&Hb[(size_t)(m0 + row) * 512 + k0 + cb * 8], Apt + q * 1024);
    }
    #pragma unroll
    for (int s = 0; s < 2; ++s) {    // B: 8 chunks
      int q = s * 4 + wave;
      int L = q * 64 + lane;
      int row = L >> 3;
      int cb = (L & 7) ^ (row & 7);
      GLD16(&WTall[(size_t)(n0 + row) * 512 + k0 + cb * 8], Bpt + q * 1024);
    }
  };

  stage(0, 0);
  __syncthreads();
  for (int it = 0; it < 8; ++it) {
    int cur = it & 1;
    if (it < 7) stage((it + 1) * 64, cur ^ 1);
    const char* Al = (const char*)(S + cur * 12288);
    const char* Bl = (const char*)(S + cur * 12288 + 8192);
    #pragma unroll
    for (int half = 0; half < 2; ++half) {
      s16x8 af[2], bfr[4];
      #pragma unroll
      for (int mi = 0; mi < 2; ++mi) {
        int ar = wave * 32 + mi * 16 + ln;
        int cbp = (qd + half * 4) ^ (ar & 7);
        af[mi] = *(const s16x8*)(Al + ar * 128 + cbp * 16);
      }
      #pragma unroll
      for (int ni = 0; ni < 4; ++ni) {
        int br = ni * 16 + ln;
        int cbp = (qd + half * 4) ^ (br & 7);
        bfr[ni] = *(const s16x8*)(Bl + br * 128 + cbp * 16);
      }
      #pragma unroll
      for (int mi = 0; mi < 2; ++mi)
        #pragma unroll
        for (int ni = 0; ni < 4; ++ni)
          acc[mi][ni] = __builtin_amdgcn_mfma_f32_16x16x32_bf16(
              af[mi], bfr[ni], acc[mi][ni], 0, 0, 0);
    }
    __syncthreads();   // single drain: loads for it+1 had full MFMA phase
  }

  int mat = gh >> 3, head = gh & 7;
  const float* nw = (mat == 0) ? qnw : knw;
  bool do_rope = (mat < 2);
  int mrow0 = m0 + wave * 32;
  int b = mrow0 >> 11, tb = mrow0 & (Tt - 1);

  #pragma unroll
  for (int mi = 0; mi < 2; ++mi) {
    float vals[4][4];
    #pragma unroll
    for (int ni = 0; ni < 4; ++ni)
      #pragma unroll
      for (int r = 0; r < 4; ++r) vals[ni][r] = acc[mi][ni][r];

    if (do_rope) {
      #pragma unroll
      for (int r = 0; r < 4; ++r) {
        float ss = 0.f;
        #pragma unroll
        for (int ni = 0; ni < 4; ++ni) ss += vals[ni][r] * vals[ni][r];
        ss += __shfl_xor(ss, 1, 64);
        ss += __shfl_xor(ss, 2, 64);
        ss += __shfl_xor(ss, 4, 64);
        ss += __shfl_xor(ss, 8, 64);
        float nrm = rsqrtf(ss * (1.0f / 64.0f) + 1e-6f);
        #pragma unroll
        for (int ni = 0; ni < 4; ++ni) vals[ni][r] *= nrm;
      }
      #pragma unroll
      for (int ni = 0; ni < 4; ++ni) {
        float w = nw[ni * 16 + ln];
        #pragma unroll
        for (int r = 0; r < 4; ++r) vals[ni][r] *= w;
      }
      float res[4][4];
      #pragma unroll
      for (int r = 0; r < 4; ++r) {
        int t = tb + mi * 16 + qd * 4 + r;
        #pragma unroll
        for (int ni = 0; ni < 4; ++ni) {
          int c = ni * 16 + ln;
          float cs = rcos[t * 64 + c];
          float sn = rsin[t * 64 + c];
          float part = vals[ni ^ 2][r];
          float rot = (ni < 2) ? -part : part;
          res[ni][r] = vals[ni][r] * cs + rot * sn;
        }
      }
      #pragma unroll
      for (int ni = 0; ni < 4; ++ni)
        #pragma unroll
        for (int r = 0; r < 4; ++r) vals[ni][r] = res[ni][r];
    }

    if (mat < 2) {   // [t_local 32][c 64] pad 72, wave-private
      unsigned short* Wl = S + wave * 2304;
      #pragma unroll
      for (int ni = 0; ni < 4; ++ni)
        #pragma unroll
        for (int r = 0; r < 4; ++r)
          Wl[(mi * 16 + qd * 4 + r) * 72 + ni * 16 + ln] = f2bf(vals[ni][r]);
    } else {         // V: [c 64][t_local 32] pad 40
      unsigned short* Wl = S + wave * 2560;
      #pragma unroll
      for (int ni = 0; ni < 4; ++ni)
        #pragma unroll
        for (int r = 0; r < 4; ++r)
          Wl[(ni * 16 + ln) * 40 + mi * 16 + qd * 4 + r] = f2bf(vals[ni][r]);
    }
  }

  if (mat < 2) {
    unsigned short* Wl = S + wave * 2304;
    unsigned short* Og =
        ((mat == 0) ? Qw : Kw) + (((size_t)b * Hh + head) * Tt + tb) * 64;
    #pragma unroll
    for (int i = 0; i < 4; ++i) {    // 32 rows x 64 = 256 chunks
      int idx = i * 64 + lane;
      int rr = idx >> 3, cc = (idx & 7) * 8;
      *(u16x8*)&Og[rr * 64 + cc] = *(const u16x8*)&Wl[rr * 72 + cc];
    }
  } else {
    unsigned short* Wl = S + wave * 2560;
    unsigned short* Og = Vw + ((size_t)b * Hh + head) * 64 * 2048 + tb;
    #pragma unroll
    for (int i = 0; i < 4; ++i) {    // 64 c-rows x 32 t = 256 chunks
      int idx = i * 64 + lane;
      int rr = idx >> 2, cc = (idx & 3) * 8;
      *(u16x8*)&Og[(size_t)rr * 2048 + cc] = *(const u16x8*)&Wl[rr * 40 + cc];
    }
  }
}

// ---------- MFMA sliding-window attention: 64 queries / block ---------------
// Q,K: (B,H,T,C); V: (B,H,C,T). AO: (B,T,H,C). 48 KB LDS.
// v4 = round-1 kernel + (a) window-aware MFMA pruning: wave w's 16 queries
// attend keys (16w, 16w+143] only -> QK nt in [w, w+8] (9 of 12), PV s in
// [w>>1, (w>>1)+4] (5 of 6); wave-uniform guards, skipped tiles provably
// masked/zero. (b) T14: V-stage issued AFTER barrier 1, flies under QK,
// drained by barrier 2's mandatory vmcnt(0).
__global__ __launch_bounds__(256) void attn_mfma(
    const unsigned short* __restrict__ Q,
    const unsigned short* __restrict__ K,
    const unsigned short* __restrict__ Vg,
    unsigned short* __restrict__ AO) {
  __shared__ alignas(16) unsigned short KP[192 * 64];  // K tile; then P[64][192]
  __shared__ alignas(16) unsigned short Vt[64 * 192];  // [c][kk] swizzled
  int tid = threadIdx.x;
  int wave = tid >> 6, lane = tid & 63;
  int ln = lane & 15, qd = lane >> 4;
  int id = (int)blockIdx.x + 32 * (int)blockIdx.y;
  int swb = (id & 7) * 64 + (id >> 3);
  int t0 = (swb & 31) * 64, bh = swb >> 5;
  int kb = t0 - 128;
  int q0 = wave * 16;

  const unsigned short* Kg = K + (size_t)bh * Tt * 64;
  const unsigned short* Vb = Vg + (size_t)bh * 64 * 2048;

  // --- async stage K: 192 rows x 64 shorts = 24 chunks of 1 KB ---
  #pragma unroll
  for (int s = 0; s < 6; ++s) {
    int q = s * 4 + wave;
    int L = q * 64 + lane;
    int row = L >> 3;
    int kg = kb + row; if (kg < 0) kg = 0;   // garbage row, masked by P=0
    int cb = (L & 7) ^ (row & 7);
    GLD16(&Kg[(size_t)kg * 64 + cb * 8], (char*)KP + q * 1024);
  }
  const unsigned short* Qg = Q + ((size_t)bh * Tt + t0 + q0) * 64;
  s16x8 aq0 = *(const s16x8*)&Qg[ln * 64 + qd * 8];
  s16x8 aq1 = *(const s16x8*)&Qg[ln * 64 + 32 + qd * 8];
  __syncthreads();   // drains K staging + Q loads only

  // --- async stage V AFTER barrier 1: overlaps QK MFMA, drained by barrier 2.
  // kb<0 source lands in preceding K storage -- finite garbage, masked by P=0.
  #pragma unroll
  for (int s = 0; s < 6; ++s) {
    int q = s * 4 + wave;
    int L = q * 64 + lane;
    int row = L / 24;
    int c24 = L - row * 24;
    int cb = (c24 & ~7) | ((c24 & 7) ^ (row & 7));
    GLD16(&Vb[(size_t)row * 2048 + kb + cb * 8], (char*)Vt + q * 1024);
  }

  int swk0 = ((qd) ^ (ln & 7)) * 8;        // stored chunk of global chunk qd
  int swk1 = ((qd + 4) ^ (ln & 7)) * 8;    // stored chunk of global chunk 4+qd
  f32x4 sf[12];
  __builtin_amdgcn_s_setprio(1);
  #pragma unroll
  for (int nt = 0; nt < 12; ++nt) {
    f32x4 a = {0.f, 0.f, 0.f, 0.f};
    if (nt >= wave && nt <= wave + 8) {   // wave-uniform window prune
      const unsigned short* kr = &KP[(nt * 16 + ln) * 64];
      s16x8 b0 = *(const s16x8*)&kr[swk0];
      s16x8 b1 = *(const s16x8*)&kr[swk1];
      a = __builtin_amdgcn_mfma_f32_16x16x32_bf16(aq0, b0, a, 0, 0, 0);
      a = __builtin_amdgcn_mfma_f32_16x16x32_bf16(aq1, b1, a, 0, 0, 0);
    }
    sf[nt] = a;
  }
  __builtin_amdgcn_s_setprio(0);
  __syncthreads();  // K reads done (safe to overwrite KP with P); V landed

  unsigned short* Pl = KP;
  int ok0 = (t0 < 128) ? (128 - t0) : 0;
  #pragma unroll
  for (int r = 0; r < 4; ++r) {
    int lq = q0 + qd * 4 + r;
    float mx = -INFINITY;
    #pragma unroll
    for (int nt = 0; nt < 12; ++nt) {
      int kk = nt * 16 + ln;
      bool valid = (kk > lq) && (kk <= lq + 128) && (kk >= ok0);
      float s = valid ? sf[nt][r] * 0.125f : -INFINITY;
      sf[nt][r] = s;
      mx = fmaxf(mx, s);
    }
    mx = fmaxf(mx, __shfl_xor(mx, 1, 64));
    mx = fmaxf(mx, __shfl_xor(mx, 2, 64));
    mx = fmaxf(mx, __shfl_xor(mx, 4, 64));
    mx = fmaxf(mx, __shfl_xor(mx, 8, 64));
    float sum = 0.f;
    #pragma unroll
    for (int nt = 0; nt < 12; ++nt) {
      float e = __expf(sf[nt][r] - mx);
      sf[nt][r] = e;
      sum += e;
    }
    sum += __shfl_xor(sum, 1, 64);
    sum += __shfl_xor(sum, 2, 64);
    sum += __shfl_xor(sum, 4, 64);
    sum += __shfl_xor(sum, 8, 64);
    float inv = 1.0f / sum;
    #pragma unroll
    for (int nt = 0; nt < 12; ++nt) {
      int kk = nt * 16 + ln;
      int c = kk >> 3;
      int swc = (c & ~7) | ((c & 7) ^ (lq & 7));
      Pl[lq * 192 + swc * 8 + (kk & 7)] = f2bf(sf[nt][r] * inv);
    }
  }
  // no barrier: P rows + O-stage region are wave-private, Vt stable

  f32x4 oa[4] = {f32x4{0,0,0,0}, f32x4{0,0,0,0}, f32x4{0,0,0,0}, f32x4{0,0,0,0}};
  int smin = wave >> 1;                    // PV window prune: s in [smin, smin+4]
  __builtin_amdgcn_s_setprio(1);
  #pragma unroll
  for (int s = 0; s < 6; ++s) {
    if (s >= smin && s <= smin + 4) {      // wave-uniform; skipped chunks have P=0
      int c = s * 4 + qd;                           // global chunk 0..23
      int swc = (c & ~7) | ((c & 7) ^ (ln & 7));    // row&7 == ln&7 for P and V
      s16x8 ap = *(const s16x8*)&Pl[(q0 + ln) * 192 + swc * 8];
      #pragma unroll
      for (int nt = 0; nt < 4; ++nt) {
        s16x8 bv = *(const s16x8*)&Vt[(nt * 16 + ln) * 192 + swc * 8];
        oa[nt] = __builtin_amdgcn_mfma_f32_16x16x32_bf16(ap, bv, oa[nt], 0, 0, 0);
      }
    }
  }
  __builtin_amdgcn_s_setprio(0);

  unsigned short* Ow = KP + q0 * 192;   // overlay this wave's P rows
  #pragma unroll
  for (int ni = 0; ni < 4; ++ni)
    #pragma unroll
    for (int r = 0; r < 4; ++r)
      Ow[(qd * 4 + r) * 72 + ni * 16 + ln] = f2bf(oa[ni][r]);
  int b = bh >> 3, h = bh & 7;
  #pragma unroll
  for (int i = 0; i < 2; ++i) {
    int idx = i * 64 + lane;
    int rr = idx >> 3, cc = (idx & 7) * 8;
    *(u16x8*)&AO[((size_t)(b * Tt + t0 + q0 + rr) * Hh + h) * 64 + cc] =
        *(const u16x8*)&Ow[rr * 72 + cc];
  }
}

// ------------- output GEMM (64x64 tile, dbuf LDS): AO @ W_o -> f32 ----------
__global__ __launch_bounds__(256) void out_gemm(
    const unsigned short* __restrict__ Am,  // (4096,512) bf16
    const unsigned short* __restrict__ WT,  // (512,512) bf16 [n][k]
    float* __restrict__ Out) {              // (4096,512) f32
  // 32 KB: buffer b at S + b*8192 (A 64x64 = 4096 shorts, B same)
  __shared__ alignas(16) unsigned short S[16384];
  int tid = threadIdx.x;
  int wave = tid >> 6, lane = tid & 63;
  int ln = lane & 15, qd = lane >> 4;
  int wm = wave >> 1, wn = wave & 1;
  int id = (int)blockIdx.x + 64 * (int)blockIdx.y;
  int swb = (id & 7) * 64 + (id >> 3);
  int m0 = (swb & 63) * 64, n0 = (swb >> 6) * 64;

  f32x4 acc[2][2];
  #pragma unroll
  for (int mi = 0; mi < 2; ++mi)
    #pragma unroll
    for (int ni = 0; ni < 2; ++ni) acc[mi][ni] = f32x4{0.f, 0.f, 0.f, 0.f};

  auto stage = [&](int k0, int buf) {
    char* Apt = (char*)(S + buf * 8192);
    char* Bpt = (char*)(S + buf * 8192 + 4096);
    #pragma unroll
    for (int s = 0; s < 2; ++s) {
      int q = s * 4 + wave;
      int L = q * 64 + lane;
      int row = L >> 3;
      int cb = (L & 7) ^ (row & 7);
      GLD16(&Am[(size_t)(m0 + row) * 512 + k0 + cb * 8], Apt + q * 1024);
      GLD16(&WT[(size_t)(n0 + row) * 512 + k0 + cb * 8], Bpt + q * 1024);
    }
  };

  stage(0, 0);
  __syncthreads();
  for (int it = 0; it < 8; ++it) {
    int cur = it & 1;
    if (it < 7) stage((it + 1) * 64, cur ^ 1);
    const char* Al = (const char*)(S + cur * 8192);
    const char* Bl = (const char*)(S + cur * 8192 + 4096);
    #pragma unroll
    for (int half = 0; half < 2; ++half) {
      s16x8 af[2], bfr[2];
      #pragma unroll
      for (int mi = 0; mi < 2; ++mi) {
        int ar = wm * 32 + mi * 16 + ln;
        int cbp = (qd + half * 4) ^ (ar & 7);
        af[mi] = *(const s16x8*)(Al + ar * 128 + cbp * 16);
      }
      #pragma unroll
      for (int ni = 0; ni < 2; ++ni) {
        int br = wn * 32 + ni * 16 + ln;
        int cbp = (qd + half * 4) ^ (br & 7);
        bfr[ni] = *(const s16x8*)(Bl + br * 128 + cbp * 16);
      }
      #pragma unroll
      for (int mi = 0; mi < 2; ++mi)
        #pragma unroll
        for (int ni = 0; ni < 2; ++ni)
          acc[mi][ni] = __builtin_amdgcn_mfma_f32_16x16x32_bf16(
              af[mi], bfr[ni], acc[mi][ni], 0, 0, 0);
    }
    __syncthreads();
  }

  #pragma unroll
  for (int mi = 0; mi < 2; ++mi)
    #pragma unroll
    for (int r = 0; r < 4; ++r) {
      int row = m0 + wm * 32 + mi * 16 + qd * 4 + r;
      #pragma unroll
      for (int ni = 0; ni < 2; ++ni)
        Out[(size_t)row * 512 + n0 + wn * 32 + ni * 16 + ln] = acc[mi][ni][r];
    }
}

extern "C" void kernel_launch(void* const* d_in, const int* in_sizes, int n_in,
                              void* d_out, int out_size, void* d_ws,
                              size_t ws_size, hipStream_t stream) {
  const float* h   = (const float*)d_in[0];
  const float* rc  = (const float*)d_in[1];
  const float* rs  = (const float*)d_in[2];
  const float* Wq  = (const float*)d_in[3];
  const float* Wk  = (const float*)d_in[4];
  const float* Wv  = (const float*)d_in[5];
  const float* Wo  = (const float*)d_in[6];
  const float* qnw = (const float*)d_in[7];
  const float* knw = (const float*)d_in[8];

  unsigned short* ws    = (unsigned short*)d_ws;
  unsigned short* WTall = ws;                       // 1536*512 (q,k,v contiguous)
  unsigned short* WTo   = WTall + 1536 * 512;       // 512*512
  unsigned short* Hb    = WTo + 512 * 512;          // 4096*512 bf16
  unsigned short* Qw    = Hb + 2097152;             // (B,H,T,C)
  unsigned short* Kw    = Qw + 2097152;             // (B,H,T,C)
  unsigned short* Vw    = Kw + 2097152;             // (B,H,C,T)
  unsigned short* AOw   = Vw + 2097152;             // (B,T,H,C)

  prep_all<<<dim3(8, 8, 5), 256, 0, stream>>>(Wq, Wk, Wv, Wo, WTall, h, Hb);

  qkv_fused<<<dim3(32, 24), 256, 0, stream>>>(Hb, WTall, qnw, knw, rc, rs,
                                              Qw, Kw, Vw);

  attn_mfma<<<dim3(32, 16), 256, 0, stream>>>(Qw, Kw, Vw, AOw);

  out_gemm<<<dim3(64, 8), 256, 0, stream>>>(AOw, WTo, (float*)d_out);
}

// Round 6
// 104.584 us; speedup vs baseline: 1.0576x; 1.0178x over previous
//
#include <hip/hip_runtime.h>
#include <hip/hip_bf16.h>
#include <cmath>

#define Tt 2048
#define Hh 8

using u16x8 = __attribute__((ext_vector_type(8))) unsigned short;
using s16x8 = __attribute__((ext_vector_type(8))) short;
using f32x4 = __attribute__((ext_vector_type(4))) float;

__device__ __forceinline__ unsigned short f2bf(float f) {
  __hip_bfloat16 b = __float2bfloat16(f);
  return *reinterpret_cast<unsigned short*>(&b);
}

// async global->LDS, 16B/lane; dest = uniform base + lane*16 (m97/m104)
#define GLD16(gp, lp)                                                        \
  __builtin_amdgcn_global_load_lds(                                          \
      (const __attribute__((address_space(1))) unsigned int*)(gp),           \
      (__attribute__((address_space(3))) unsigned int*)(lp), 16, 0, 0)

// ---- prep: z<4 -> transpose+cvt weight z into WTall; z==4 -> cvt h ---------
__global__ __launch_bounds__(256) void prep_all(
    const float* __restrict__ s0, const float* __restrict__ s1,
    const float* __restrict__ s2, const float* __restrict__ s3,
    unsigned short* __restrict__ d,
    const float* __restrict__ hsrc, unsigned short* __restrict__ hdst) {
  int tid = threadIdx.x;
  if (blockIdx.z == 4) {
    int gid = ((int)blockIdx.y * 8 + blockIdx.x) * 256 + tid;  // 0..16383
    #pragma unroll
    for (int s = 0; s < 16; ++s) {
      size_t i = ((size_t)s * 16384 + gid) * 8;
      const float4* g = (const float4*)&hsrc[i];
      float4 f0 = g[0], f1 = g[1];
      u16x8 o = {f2bf(f0.x), f2bf(f0.y), f2bf(f0.z), f2bf(f0.w),
                 f2bf(f1.x), f2bf(f1.y), f2bf(f1.z), f2bf(f1.w)};
      *(u16x8*)&hdst[i] = o;
    }
    return;
  }
  __shared__ unsigned short tile[64 * 65];
  const float* srcs[4] = {s0, s1, s2, s3};
  const float* src = srcs[blockIdx.z];
  unsigned short* dst = d + (size_t)blockIdx.z * 512 * 512;
  int n0 = blockIdx.x * 64, k0 = blockIdx.y * 64;
  int tx = tid & 63, ty = tid >> 6;
  #pragma unroll
  for (int i = 0; i < 16; ++i) {
    int k = ty * 16 + i;
    tile[k * 65 + tx] = f2bf(src[(k0 + k) * 512 + n0 + tx]);
  }
  __syncthreads();
  #pragma unroll
  for (int i = 0; i < 16; ++i) {
    int n = ty * 16 + i;
    dst[(n0 + n) * 512 + k0 + tx] = tile[tx * 65 + n];
  }
}

// -------- fused QKV GEMM (128x64 tile, dbuf LDS, 1 barrier/K-iter) ----------
// grid (32, 24): XCD-swizzled. y = gh -> mat = gh>>3 (Q/K/V), head = gh&7.
// Q,K out: (B,H,T,C). V out: (B,H,C,T).
// launch_bounds(256,3): force 3 blocks/CU (VGPR cap 168; LDS already allows 3).
__global__ __launch_bounds__(256, 3) void qkv_fused(
    const unsigned short* __restrict__ Hb,     // (4096,512) bf16
    const unsigned short* __restrict__ WTall,  // (1536,512) bf16 [n][k]
    const float* __restrict__ qnw, const float* __restrict__ knw,
    const float* __restrict__ rcos, const float* __restrict__ rsin,
    unsigned short* __restrict__ Qw, unsigned short* __restrict__ Kw,
    unsigned short* __restrict__ Vw) {
  // 48 KB: buffer b at S + b*12288 (A 128x64 = 8192 shorts, B 64x64 = 4096)
  __shared__ alignas(16) unsigned short S[24576];
  int tid = threadIdx.x;
  int wave = tid >> 6, lane = tid & 63;
  int ln = lane & 15, qd = lane >> 4;
  // XCD-aware bijective swizzle: 768 blocks, 96/XCD = 3 full gh columns
  int id = (int)blockIdx.x + 32 * (int)blockIdx.y;
  int sw = (id & 7) * 96 + (id >> 3);
  int m0 = (sw & 31) * 128;
  int gh = sw >> 5;
  int n0 = gh * 64;

  f32x4 acc[2][4];
  #pragma unroll
  for (int mi = 0; mi < 2; ++mi)
    #pragma unroll
    for (int ni = 0; ni < 4; ++ni) acc[mi][ni] = f32x4{0.f, 0.f, 0.f, 0.f};

  auto stage = [&](int k0, int buf) {
    char* Apt = (char*)(S + buf * 12288);
    char* Bpt = (char*)(S + buf * 12288 + 8192);
    #pragma unroll
    for (int s = 0; s < 4; ++s) {    // A: 16 chunks of 1 KB
      int q = s * 4 + wave;
      int L = q * 64 + lane;
      int row = L >> 3;
      int cb = (L & 7) ^ (row & 7);
      GLD16(&Hb[(size_t)(m0 + row) * 512 + k0 + cb * 8], Apt + q * 1024);
    }
    #pragma unroll
    for (int s = 0; s < 2; ++s) {    // B: 8 chunks
      int q = s * 4 + wave;
      int L = q * 64 + lane;
      int row = L >> 3;
      int cb = (L & 7) ^ (row & 7);
      GLD16(&WTall[(size_t)(n0 + row) * 512 + k0 + cb * 8], Bpt + q * 1024);
    }
  };

  stage(0, 0);
  __syncthreads();
  for (int it = 0; it < 8; ++it) {
    int cur = it & 1;
    if (it < 7) stage((it + 1) * 64, cur ^ 1);
    const char* Al = (const char*)(S + cur * 12288);
    const char* Bl = (const char*)(S + cur * 12288 + 8192);
    #pragma unroll
    for (int half = 0; half < 2; ++half) {
      s16x8 af[2], bfr[4];
      #pragma unroll
      for (int mi = 0; mi < 2; ++mi) {
        int ar = wave * 32 + mi * 16 + ln;
        int cbp = (qd + half * 4) ^ (ar & 7);
        af[mi] = *(const s16x8*)(Al + ar * 128 + cbp * 16);
      }
      #pragma unroll
      for (int ni = 0; ni < 4; ++ni) {
        int br = ni * 16 + ln;
        int cbp = (qd + half * 4) ^ (br & 7);
        bfr[ni] = *(const s16x8*)(Bl + br * 128 + cbp * 16);
      }
      #pragma unroll
      for (int mi = 0; mi < 2; ++mi)
        #pragma unroll
        for (int ni = 0; ni < 4; ++ni)
          acc[mi][ni] = __builtin_amdgcn_mfma_f32_16x16x32_bf16(
              af[mi], bfr[ni], acc[mi][ni], 0, 0, 0);
    }
    __syncthreads();   // single drain: loads for it+1 had full MFMA phase
  }

  int mat = gh >> 3, head = gh & 7;
  const float* nw = (mat == 0) ? qnw : knw;
  bool do_rope = (mat < 2);
  int mrow0 = m0 + wave * 32;
  int b = mrow0 >> 11, tb = mrow0 & (Tt - 1);

  #pragma unroll
  for (int mi = 0; mi < 2; ++mi) {
    float vals[4][4];
    #pragma unroll
    for (int ni = 0; ni < 4; ++ni)
      #pragma unroll
      for (int r = 0; r < 4; ++r) vals[ni][r] = acc[mi][ni][r];

    if (do_rope) {
      #pragma unroll
      for (int r = 0; r < 4; ++r) {
        float ss = 0.f;
        #pragma unroll
        for (int ni = 0; ni < 4; ++ni) ss += vals[ni][r] * vals[ni][r];
        ss += __shfl_xor(ss, 1, 64);
        ss += __shfl_xor(ss, 2, 64);
        ss += __shfl_xor(ss, 4, 64);
        ss += __shfl_xor(ss, 8, 64);
        float nrm = rsqrtf(ss * (1.0f / 64.0f) + 1e-6f);
        #pragma unroll
        for (int ni = 0; ni < 4; ++ni) vals[ni][r] *= nrm;
      }
      #pragma unroll
      for (int ni = 0; ni < 4; ++ni) {
        float w = nw[ni * 16 + ln];
        #pragma unroll
        for (int r = 0; r < 4; ++r) vals[ni][r] *= w;
      }
      float res[4][4];
      #pragma unroll
      for (int r = 0; r < 4; ++r) {
        int t = tb + mi * 16 + qd * 4 + r;
        #pragma unroll
        for (int ni = 0; ni < 4; ++ni) {
          int c = ni * 16 + ln;
          float cs = rcos[t * 64 + c];
          float sn = rsin[t * 64 + c];
          float part = vals[ni ^ 2][r];
          float rot = (ni < 2) ? -part : part;
          res[ni][r] = vals[ni][r] * cs + rot * sn;
        }
      }
      #pragma unroll
      for (int ni = 0; ni < 4; ++ni)
        #pragma unroll
        for (int r = 0; r < 4; ++r) vals[ni][r] = res[ni][r];
    }

    if (mat < 2) {   // [t_local 32][c 64] pad 72, wave-private
      unsigned short* Wl = S + wave * 2304;
      #pragma unroll
      for (int ni = 0; ni < 4; ++ni)
        #pragma unroll
        for (int r = 0; r < 4; ++r)
          Wl[(mi * 16 + qd * 4 + r) * 72 + ni * 16 + ln] = f2bf(vals[ni][r]);
    } else {         // V: [c 64][t_local 32] pad 40
      unsigned short* Wl = S + wave * 2560;
      #pragma unroll
      for (int ni = 0; ni < 4; ++ni)
        #pragma unroll
        for (int r = 0; r < 4; ++r)
          Wl[(ni * 16 + ln) * 40 + mi * 16 + qd * 4 + r] = f2bf(vals[ni][r]);
    }
  }

  if (mat < 2) {
    unsigned short* Wl = S + wave * 2304;
    unsigned short* Og =
        ((mat == 0) ? Qw : Kw) + (((size_t)b * Hh + head) * Tt + tb) * 64;
    #pragma unroll
    for (int i = 0; i < 4; ++i) {    // 32 rows x 64 = 256 chunks
      int idx = i * 64 + lane;
      int rr = idx >> 3, cc = (idx & 7) * 8;
      *(u16x8*)&Og[rr * 64 + cc] = *(const u16x8*)&Wl[rr * 72 + cc];
    }
  } else {
    unsigned short* Wl = S + wave * 2560;
    unsigned short* Og = Vw + ((size_t)b * Hh + head) * 64 * 2048 + tb;
    #pragma unroll
    for (int i = 0; i < 4; ++i) {    // 64 c-rows x 32 t = 256 chunks
      int idx = i * 64 + lane;
      int rr = idx >> 2, cc = (idx & 3) * 8;
      *(u16x8*)&Og[(size_t)rr * 2048 + cc] = *(const u16x8*)&Wl[rr * 40 + cc];
    }
  }
}

// ---------- MFMA sliding-window attention: 64 queries / block ---------------
// Q,K: (B,H,T,C); V: (B,H,C,T). AO: (B,T,H,C). 48 KB LDS.
// Round-1 verified kernel; launch_bounds(256,3) forces 3 blocks/CU
// (VGPR cap 168; LDS already allows 3).
__global__ __launch_bounds__(256, 3) void attn_mfma(
    const unsigned short* __restrict__ Q,
    const unsigned short* __restrict__ K,
    const unsigned short* __restrict__ Vg,
    unsigned short* __restrict__ AO) {
  __shared__ alignas(16) unsigned short KP[192 * 64];  // K tile; then P[64][192]
  __shared__ alignas(16) unsigned short Vt[64 * 192];  // [c][kk] swizzled
  int tid = threadIdx.x;
  int wave = tid >> 6, lane = tid & 63;
  int ln = lane & 15, qd = lane >> 4;
  int id = (int)blockIdx.x + 32 * (int)blockIdx.y;
  int swb = (id & 7) * 64 + (id >> 3);
  int t0 = (swb & 31) * 64, bh = swb >> 5;
  int kb = t0 - 128;
  int q0 = wave * 16;

  const unsigned short* Kg = K + (size_t)bh * Tt * 64;
  const unsigned short* Vb = Vg + (size_t)bh * 64 * 2048;

  // --- async stage K: 192 rows x 64 shorts = 24 chunks of 1 KB ---
  #pragma unroll
  for (int s = 0; s < 6; ++s) {
    int q = s * 4 + wave;
    int L = q * 64 + lane;
    int row = L >> 3;
    int kg = kb + row; if (kg < 0) kg = 0;   // garbage row, masked by P=0
    int cb = (L & 7) ^ (row & 7);
    GLD16(&Kg[(size_t)kg * 64 + cb * 8], (char*)KP + q * 1024);
  }
  // --- async stage V: 64 rows x 192 shorts = 24 chunks ---
  // kb<0 source lands in preceding K storage -- finite garbage, masked.
  #pragma unroll
  for (int s = 0; s < 6; ++s) {
    int q = s * 4 + wave;
    int L = q * 64 + lane;
    int row = L / 24;
    int c24 = L - row * 24;
    int cb = (c24 & ~7) | ((c24 & 7) ^ (row & 7));
    GLD16(&Vb[(size_t)row * 2048 + kb + cb * 8], (char*)Vt + q * 1024);
  }
  const unsigned short* Qg = Q + ((size_t)bh * Tt + t0 + q0) * 64;
  s16x8 aq0 = *(const s16x8*)&Qg[ln * 64 + qd * 8];
  s16x8 aq1 = *(const s16x8*)&Qg[ln * 64 + 32 + qd * 8];
  __syncthreads();   // vmcnt drain: staging + Q complete

  int swk0 = ((qd) ^ (ln & 7)) * 8;        // stored chunk of global chunk qd
  int swk1 = ((qd + 4) ^ (ln & 7)) * 8;    // stored chunk of global chunk 4+qd
  f32x4 sf[12];
  __builtin_amdgcn_s_setprio(1);
  #pragma unroll
  for (int nt = 0; nt < 12; ++nt) {
    const unsigned short* kr = &KP[(nt * 16 + ln) * 64];
    s16x8 b0 = *(const s16x8*)&kr[swk0];
    s16x8 b1 = *(const s16x8*)&kr[swk1];
    f32x4 a = {0.f, 0.f, 0.f, 0.f};
    a = __builtin_amdgcn_mfma_f32_16x16x32_bf16(aq0, b0, a, 0, 0, 0);
    a = __builtin_amdgcn_mfma_f32_16x16x32_bf16(aq1, b1, a, 0, 0, 0);
    sf[nt] = a;
  }
  __builtin_amdgcn_s_setprio(0);
  __syncthreads();  // K reads done; safe to overwrite KP with P

  unsigned short* Pl = KP;
  int ok0 = (t0 < 128) ? (128 - t0) : 0;
  #pragma unroll
  for (int r = 0; r < 4; ++r) {
    int lq = q0 + qd * 4 + r;
    float mx = -INFINITY;
    #pragma unroll
    for (int nt = 0; nt < 12; ++nt) {
      int kk = nt * 16 + ln;
      bool valid = (kk > lq) && (kk <= lq + 128) && (kk >= ok0);
      float s = valid ? sf[nt][r] * 0.125f : -INFINITY;
      sf[nt][r] = s;
      mx = fmaxf(mx, s);
    }
    mx = fmaxf(mx, __shfl_xor(mx, 1, 64));
    mx = fmaxf(mx, __shfl_xor(mx, 2, 64));
    mx = fmaxf(mx, __shfl_xor(mx, 4, 64));
    mx = fmaxf(mx, __shfl_xor(mx, 8, 64));
    float sum = 0.f;
    #pragma unroll
    for (int nt = 0; nt < 12; ++nt) {
      float e = __expf(sf[nt][r] - mx);
      sf[nt][r] = e;
      sum += e;
    }
    sum += __shfl_xor(sum, 1, 64);
    sum += __shfl_xor(sum, 2, 64);
    sum += __shfl_xor(sum, 4, 64);
    sum += __shfl_xor(sum, 8, 64);
    float inv = 1.0f / sum;
    #pragma unroll
    for (int nt = 0; nt < 12; ++nt) {
      int kk = nt * 16 + ln;
      int c = kk >> 3;
      int swc = (c & ~7) | ((c & 7) ^ (lq & 7));
      Pl[lq * 192 + swc * 8 + (kk & 7)] = f2bf(sf[nt][r] * inv);
    }
  }
  // no barrier: P rows + O-stage region are wave-private, Vt stable

  f32x4 oa[4] = {f32x4{0,0,0,0}, f32x4{0,0,0,0}, f32x4{0,0,0,0}, f32x4{0,0,0,0}};
  __builtin_amdgcn_s_setprio(1);
  #pragma unroll
  for (int s = 0; s < 6; ++s) {
    int c = s * 4 + qd;                           // global chunk 0..23
    int swc = (c & ~7) | ((c & 7) ^ (ln & 7));    // row&7 == ln&7 for P and V
    s16x8 ap = *(const s16x8*)&Pl[(q0 + ln) * 192 + swc * 8];
    #pragma unroll
    for (int nt = 0; nt < 4; ++nt) {
      s16x8 bv = *(const s16x8*)&Vt[(nt * 16 + ln) * 192 + swc * 8];
      oa[nt] = __builtin_amdgcn_mfma_f32_16x16x32_bf16(ap, bv, oa[nt], 0, 0, 0);
    }
  }
  __builtin_amdgcn_s_setprio(0);

  unsigned short* Ow = KP + q0 * 192;   // overlay this wave's P rows
  #pragma unroll
  for (int ni = 0; ni < 4; ++ni)
    #pragma unroll
    for (int r = 0; r < 4; ++r)
      Ow[(qd * 4 + r) * 72 + ni * 16 + ln] = f2bf(oa[ni][r]);
  int b = bh >> 3, h = bh & 7;
  #pragma unroll
  for (int i = 0; i < 2; ++i) {
    int idx = i * 64 + lane;
    int rr = idx >> 3, cc = (idx & 7) * 8;
    *(u16x8*)&AO[((size_t)(b * Tt + t0 + q0 + rr) * Hh + h) * 64 + cc] =
        *(const u16x8*)&Ow[rr * 72 + cc];
  }
}

// ------------- output GEMM (64x64 tile, dbuf LDS): AO @ W_o -> f32 ----------
// launch_bounds(256,4): VGPR cap 128 (kernel needs ~70); ensures >=4 blocks/CU.
__global__ __launch_bounds__(256, 4) void out_gemm(
    const unsigned short* __restrict__ Am,  // (4096,512) bf16
    const unsigned short* __restrict__ WT,  // (512,512) bf16 [n][k]
    float* __restrict__ Out) {              // (4096,512) f32
  // 32 KB: buffer b at S + b*8192 (A 64x64 = 4096 shorts, B same)
  __shared__ alignas(16) unsigned short S[16384];
  int tid = threadIdx.x;
  int wave = tid >> 6, lane = tid & 63;
  int ln = lane & 15, qd = lane >> 4;
  int wm = wave >> 1, wn = wave & 1;
  int id = (int)blockIdx.x + 64 * (int)blockIdx.y;
  int swb = (id & 7) * 64 + (id >> 3);
  int m0 = (swb & 63) * 64, n0 = (swb >> 6) * 64;

  f32x4 acc[2][2];
  #pragma unroll
  for (int mi = 0; mi < 2; ++mi)
    #pragma unroll
    for (int ni = 0; ni < 2; ++ni) acc[mi][ni] = f32x4{0.f, 0.f, 0.f, 0.f};

  auto stage = [&](int k0, int buf) {
    char* Apt = (char*)(S + buf * 8192);
    char* Bpt = (char*)(S + buf * 8192 + 4096);
    #pragma unroll
    for (int s = 0; s < 2; ++s) {
      int q = s * 4 + wave;
      int L = q * 64 + lane;
      int row = L >> 3;
      int cb = (L & 7) ^ (row & 7);
      GLD16(&Am[(size_t)(m0 + row) * 512 + k0 + cb * 8], Apt + q * 1024);
      GLD16(&WT[(size_t)(n0 + row) * 512 + k0 + cb * 8], Bpt + q * 1024);
    }
  };

  stage(0, 0);
  __syncthreads();
  for (int it = 0; it < 8; ++it) {
    int cur = it & 1;
    if (it < 7) stage((it + 1) * 64, cur ^ 1);
    const char* Al = (const char*)(S + cur * 8192);
    const char* Bl = (const char*)(S + cur * 8192 + 4096);
    #pragma unroll
    for (int half = 0; half < 2; ++half) {
      s16x8 af[2], bfr[2];
      #pragma unroll
      for (int mi = 0; mi < 2; ++mi) {
        int ar = wm * 32 + mi * 16 + ln;
        int cbp = (qd + half * 4) ^ (ar & 7);
        af[mi] = *(const s16x8*)(Al + ar * 128 + cbp * 16);
      }
      #pragma unroll
      for (int ni = 0; ni < 2; ++ni) {
        int br = wn * 32 + ni * 16 + ln;
        int cbp = (qd + half * 4) ^ (br & 7);
        bfr[ni] = *(const s16x8*)(Bl + br * 128 + cbp * 16);
      }
      #pragma unroll
      for (int mi = 0; mi < 2; ++mi)
        #pragma unroll
        for (int ni = 0; ni < 2; ++ni)
          acc[mi][ni] = __builtin_amdgcn_mfma_f32_16x16x32_bf16(
              af[mi], bfr[ni], acc[mi][ni], 0, 0, 0);
    }
    __syncthreads();
  }

  #pragma unroll
  for (int mi = 0; mi < 2; ++mi)
    #pragma unroll
    for (int r = 0; r < 4; ++r) {
      int row = m0 + wm * 32 + mi * 16 + qd * 4 + r;
      #pragma unroll
      for (int ni = 0; ni < 2; ++ni)
        Out[(size_t)row * 512 + n0 + wn * 32 + ni * 16 + ln] = acc[mi][ni][r];
    }
}

extern "C" void kernel_launch(void* const* d_in, const int* in_sizes, int n_in,
                              void* d_out, int out_size, void* d_ws,
                              size_t ws_size, hipStream_t stream) {
  const float* h   = (const float*)d_in[0];
  const float* rc  = (const float*)d_in[1];
  const float* rs  = (const float*)d_in[2];
  const float* Wq  = (const float*)d_in[3];
  const float* Wk  = (const float*)d_in[4];
  const float* Wv  = (const float*)d_in[5];
  const float* Wo  = (const float*)d_in[6];
  const float* qnw = (const float*)d_in[7];
  const float* knw = (const float*)d_in[8];

  unsigned short* ws    = (unsigned short*)d_ws;
  unsigned short* WTall = ws;                       // 1536*512 (q,k,v contiguous)
  unsigned short* WTo   = WTall + 1536 * 512;       // 512*512
  unsigned short* Hb    = WTo + 512 * 512;          // 4096*512 bf16
  unsigned short* Qw    = Hb + 2097152;             // (B,H,T,C)
  unsigned short* Kw    = Qw + 2097152;             // (B,H,T,C)
  unsigned short* Vw    = Kw + 2097152;             // (B,H,C,T)
  unsigned short* AOw   = Vw + 2097152;             // (B,T,H,C)

  prep_all<<<dim3(8, 8, 5), 256, 0, stream>>>(Wq, Wk, Wv, Wo, WTall, h, Hb);

  qkv_fused<<<dim3(32, 24), 256, 0, stream>>>(Hb, WTall, qnw, knw, rc, rs,
                                              Qw, Kw, Vw);

  attn_mfma<<<dim3(32, 16), 256, 0, stream>>>(Qw, Kw, Vw, AOw);

  out_gemm<<<dim3(64, 8), 256, 0, stream>>>(AOw, WTo, (float*)d_out);
}